// Round 14
// baseline (899.460 us; speedup 1.0000x reference)
//
#include <hip/hip_runtime.h>
#include <stdint.h>

#define T_TOK 8192
#define DM 1024
#define HID 4096
#define NE 8
#define RP2 18432      // 16384 + 8*256 worst-case rows padded to 256
#define MT128 144      // RP2 / 128
#define MT256 72       // RP2 / 256

typedef unsigned short u16;
typedef __attribute__((ext_vector_type(4))) float f32x4;
typedef __attribute__((ext_vector_type(8))) __bf16 bf16x8;

#define GLB(p) ((const __attribute__((address_space(1))) unsigned int*)(p))
#define LDSP(p) ((__attribute__((address_space(3))) unsigned int*)(p))

__device__ __forceinline__ u16 f2bf(float f) {
    union { float f; unsigned u; } c; c.f = f;
    unsigned r = (c.u + 0x7FFFu + ((c.u >> 16) & 1u)) >> 16;
    return (u16)r;
}

// ---------- 0: init counters + row_token ----------
__global__ __launch_bounds__(256) void k_init(int* counts, int* cursors, int* row_token) {
    int i = blockIdx.x * 256 + threadIdx.x;
    if (i < RP2) row_token[i] = -1;
    if (i < NE) { counts[i] = 0; cursors[i] = 0; }
}

// ---------- 1: gating (one wave per token, fp32) + fused x->bf16 convert ----------
__global__ __launch_bounds__(256) void k_gate(const float* __restrict__ x,
        const float* __restrict__ gw, const float* __restrict__ gb,
        int* __restrict__ tok_e, float* __restrict__ tok_w, int* __restrict__ counts,
        u16* __restrict__ xb) {
    int t = blockIdx.x * 4 + (threadIdx.x >> 6);
    int lane = threadIdx.x & 63;
    const float* xr = x + (size_t)t * DM;
    u16* xbr = xb + (size_t)t * DM;
    float a0=0,a1=0,a2=0,a3=0,a4=0,a5=0,a6=0,a7=0;
    for (int d = lane; d < DM; d += 64) {
        float xv = xr[d];
        xbr[d] = f2bf(xv);
        const float4* g = (const float4*)(gw + (size_t)d * NE);
        float4 g0 = g[0], g1 = g[1];
        a0 += xv*g0.x; a1 += xv*g0.y; a2 += xv*g0.z; a3 += xv*g0.w;
        a4 += xv*g1.x; a5 += xv*g1.y; a6 += xv*g1.z; a7 += xv*g1.w;
    }
    #pragma unroll
    for (int off = 32; off; off >>= 1) {
        a0 += __shfl_xor(a0, off); a1 += __shfl_xor(a1, off);
        a2 += __shfl_xor(a2, off); a3 += __shfl_xor(a3, off);
        a4 += __shfl_xor(a4, off); a5 += __shfl_xor(a5, off);
        a6 += __shfl_xor(a6, off); a7 += __shfl_xor(a7, off);
    }
    if (lane == 0) {
        float l[8] = {a0+gb[0],a1+gb[1],a2+gb[2],a3+gb[3],a4+gb[4],a5+gb[5],a6+gb[6],a7+gb[7]};
        int e0 = 0;
        #pragma unroll
        for (int e = 1; e < 8; ++e) if (l[e] > l[e0]) e0 = e;
        int e1 = (e0 == 0) ? 1 : 0;
        #pragma unroll
        for (int e = 0; e < 8; ++e) if (e != e0 && l[e] > l[e1]) e1 = e;
        float p1 = expf(l[e1] - l[e0]);
        float inv = 1.f / (1.f + p1);
        tok_e[2*t] = e0; tok_e[2*t+1] = e1;
        tok_w[2*t] = inv; tok_w[2*t+1] = p1 * inv;
        atomicAdd(&counts[e0], 1);
        atomicAdd(&counts[e1], 1);
    }
}

// ---------- 2: padded prefix (256-aligned) + count-aware tile->expert map ----------
__global__ void k_scan(const int* __restrict__ counts, int* __restrict__ pad_off,
                       int* __restrict__ tile_expert) {
    __shared__ int off[NE + 1];
    __shared__ int cnt[NE];
    if (threadIdx.x == 0) {
        int o = 0;
        for (int e = 0; e < NE; ++e) {
            off[e] = o; pad_off[e] = o; cnt[e] = counts[e];
            o += ((counts[e] + 255) >> 8) << 8;
        }
        off[NE] = o; pad_off[NE] = o;
    }
    __syncthreads();
    for (int i = threadIdx.x; i < MT128; i += blockDim.x) {
        int ex = -1, base = i * 128;
        #pragma unroll
        for (int e = 0; e < NE; ++e)
            if (base >= off[e] && base < off[e] + cnt[e]) ex = e;
        tile_expert[i] = ex;
    }
}

// ---------- 3: assign rows ----------
__global__ __launch_bounds__(256) void k_assign(const int* __restrict__ tok_e, const float* __restrict__ tok_w,
        const int* __restrict__ pad_off, int* __restrict__ cursors,
        int* __restrict__ row_token, float* __restrict__ row_weight, int* __restrict__ token_rows) {
    int t = blockIdx.x * 256 + threadIdx.x;
    if (t >= T_TOK) return;
    #pragma unroll
    for (int k = 0; k < 2; ++k) {
        int e = tok_e[2*t+k];
        int pos = atomicAdd(&cursors[e], 1);
        int r = pad_off[e] + pos;
        row_token[r] = t;
        row_weight[r] = tok_w[2*t+k];
        token_rows[2*t+k] = r;
    }
}

// ---------- 5: LDS transpose: [E][R][C] f32 -> [E][C][R] bf16 ----------
template<int R, int C>
__global__ __launch_bounds__(256) void k_transpose(const float* __restrict__ in, u16* __restrict__ out) {
    __shared__ unsigned lds[64 * 128];
    const int TR = R / 256, TC = C / 64;
    const int tiles = TR * TC;
    int e = blockIdx.x / tiles;
    int rem = blockIdx.x % tiles;
    int rt = rem / TC, ct = rem % TC;
    const float* src = in + (size_t)e * R * C + (size_t)(rt * 256) * C + ct * 64;
    u16* dst = out + (size_t)e * R * C + (size_t)(ct * 64) * R + rt * 256;
    int tid = threadIdx.x;
    int cslot = tid & 15;
    int swzA = (cslot & 7) << 2;
    #pragma unroll
    for (int i = 0; i < 8; ++i) {
        int rp = (i * 256 + tid) >> 4;
        float4 v0 = *(const float4*)&src[(size_t)(2 * rp) * C + cslot * 4];
        float4 v1 = *(const float4*)&src[(size_t)(2 * rp + 1) * C + cslot * 4];
        int base = (rp ^ swzA);
        lds[(cslot * 4 + 0) * 128 + base] = (unsigned)f2bf(v0.x) | ((unsigned)f2bf(v1.x) << 16);
        lds[(cslot * 4 + 1) * 128 + base] = (unsigned)f2bf(v0.y) | ((unsigned)f2bf(v1.y) << 16);
        lds[(cslot * 4 + 2) * 128 + base] = (unsigned)f2bf(v0.z) | ((unsigned)f2bf(v1.z) << 16);
        lds[(cslot * 4 + 3) * 128 + base] = (unsigned)f2bf(v0.w) | ((unsigned)f2bf(v1.w) << 16);
    }
    __syncthreads();
    #pragma unroll
    for (int i = 0; i < 8; ++i) {
        int idx = i * 256 + tid;
        int c = idx >> 5, rs = idx & 31;
        int swz = ((c >> 2) & 7) << 2;
        uint4 w = *(const uint4*)&lds[c * 128 + ((rs * 4) ^ swz)];
        *(uint4*)&dst[(size_t)c * R + rs * 8] = w;
    }
}

// ---------- 6a: 256x256 8-wave double-buffered GEMM (GEMM1) — R3/R7-proven ----------
template<int NBN, int N, int K, bool GATHER, bool SILU>
__global__ __launch_bounds__(512, 2) void k_gemm256(
    const u16* __restrict__ Asrc, const u16* __restrict__ Bw,
    const float* __restrict__ bias, void* __restrict__ Out,
    const int* __restrict__ row_token, const int* __restrict__ tile_expert, int mt)
{
    int id = blockIdx.x;
    int cpx = (NBN * mt) >> 3;
    int sid = (id & 7) * cpx + (id >> 3);
    int bm = sid / NBN, bn = sid % NBN;
    int e = tile_expert[2 * bm];           // 256-pad => both 128-halves same expert
    if (e < 0) return;
    int tid = threadIdx.x, wid = tid >> 6, lane = tid & 63;
    int wr = wid >> 2, wc = wid & 3;

    __shared__ u16 Al[2 * 256 * 64];
    __shared__ u16 Bl[2 * 256 * 64];

    unsigned kslb = ((unsigned)((lane & 7) ^ (lane >> 3))) * 16u;
    unsigned aoff[4], boff[4];
    #pragma unroll
    for (int i = 0; i < 4; ++i) {
        int row = (wid * 4 + i) * 8 + (lane >> 3);
        unsigned arow;
        if (GATHER) {
            int tk = row_token[bm * 256 + row];
            if (tk < 0) tk = 0;            // pad rows: duplicate token 0 (ignored)
            arow = (unsigned)tk;
        } else {
            arow = (unsigned)(bm * 256 + row);
        }
        aoff[i] = arow * (unsigned)(K * 2) + kslb;
        boff[i] = ((unsigned)e * (unsigned)N + (unsigned)(bn * 256 + row)) * (unsigned)(K * 2) + kslb;
    }

    f32x4 acc[8][4];
    #pragma unroll
    for (int m = 0; m < 8; ++m)
        #pragma unroll
        for (int n = 0; n < 4; ++n) acc[m][n] = f32x4{0.f, 0.f, 0.f, 0.f};

    auto stage = [&](int buf, int kt) {
        unsigned ko = (unsigned)kt * 128u;
        #pragma unroll
        for (int i = 0; i < 4; ++i) {
            __builtin_amdgcn_global_load_lds(GLB((const char*)Asrc + aoff[i] + ko),
                LDSP(&Al[buf * 16384 + (wid * 4 + i) * 512]), 16, 0, 0);
            __builtin_amdgcn_global_load_lds(GLB((const char*)Bw + boff[i] + ko),
                LDSP(&Bl[buf * 16384 + (wid * 4 + i) * 512]), 16, 0, 0);
        }
    };

    auto compute = [&](int buf) {
        const char* Ab = (const char*)&Al[buf * 16384];
        const char* Bb = (const char*)&Bl[buf * 16384];
        unsigned sl0 = (unsigned)(((lane >> 4) ^ (lane & 7)) << 4);
        unsigned sl1 = (unsigned)((((lane >> 4) + 4) ^ (lane & 7)) << 4);
        bf16x8 bfr[4][2];
        #pragma unroll
        for (int n = 0; n < 4; ++n) {
            unsigned br = (unsigned)(wc * 64 + n * 16 + (lane & 15)) * 128u;
            bfr[n][0] = *(const bf16x8*)(Bb + br + sl0);
            bfr[n][1] = *(const bf16x8*)(Bb + br + sl1);
        }
        __builtin_amdgcn_s_setprio(1);
        #pragma unroll
        for (int m = 0; m < 8; ++m) {
            unsigned ar = (unsigned)(wr * 128 + m * 16 + (lane & 15)) * 128u;
            bf16x8 a0 = *(const bf16x8*)(Ab + ar + sl0);
            bf16x8 a1 = *(const bf16x8*)(Ab + ar + sl1);
            #pragma unroll
            for (int n = 0; n < 4; ++n) {
                acc[m][n] = __builtin_amdgcn_mfma_f32_16x16x32_bf16(a0, bfr[n][0], acc[m][n], 0, 0, 0);
                acc[m][n] = __builtin_amdgcn_mfma_f32_16x16x32_bf16(a1, bfr[n][1], acc[m][n], 0, 0, 0);
            }
        }
        __builtin_amdgcn_s_setprio(0);
    };

    stage(0, 0);
    asm volatile("s_waitcnt vmcnt(0)" ::: "memory");
    __syncthreads();
    int cur = 0;
    const int NT = K / 64;
    for (int kt = 1; kt < NT; ++kt) {
        stage(cur ^ 1, kt);
        compute(cur);
        asm volatile("s_waitcnt vmcnt(0)" ::: "memory");
        __syncthreads();
        cur ^= 1;
    }
    compute(cur);

    int rb = bm * 256 + wr * 128 + (lane >> 4) * 4;
    int cb = bn * 256 + wc * 64 + (lane & 15);
    #pragma unroll
    for (int n = 0; n < 4; ++n) {
        int col = cb + n * 16;
        float bv = bias[e * N + col];
        #pragma unroll
        for (int m = 0; m < 8; ++m) {
            #pragma unroll
            for (int r = 0; r < 4; ++r) {
                int row = rb + m * 16 + r;
                float v = acc[m][n][r] + bv;
                if (SILU) v = v / (1.f + __expf(-v));
                ((u16*)Out)[(size_t)row * N + col] = f2bf(v);
            }
        }
    }
}

// ---------- 6b: GEMM2 — 128x256 tile, 8 waves (2M x 4N, 64x64/wave), dbuf 96KB ----------
// Staged bytes = M*N*K*2*(1/128 + 1/256) = 0.75x of the 128x128 version (the
// staging-BW theory's lever). Staging pattern + kslot XOR + sync structure are
// the R3/R7-proven ones byte-for-byte; bf16 out.
template<int N, int K>
__global__ __launch_bounds__(512, 2) void k_gemm2(
    const u16* __restrict__ Asrc, const u16* __restrict__ Bw,
    const float* __restrict__ bias, u16* __restrict__ Out,
    const int* __restrict__ tile_expert, int mt)
{
    constexpr int NBN = N / 256;
    int id = blockIdx.x;
    int cpx = (NBN * mt) >> 3;
    int sid = (id & 7) * cpx + (id >> 3);
    int bm = sid / NBN, bn = sid % NBN;
    int e = tile_expert[bm];
    if (e < 0) return;
    int tid = threadIdx.x, wid = tid >> 6, lane = tid & 63;
    int wr = wid >> 2, wc = wid & 3;       // 2M x 4N waves, 64x64 per wave
    int l15 = lane & 15, l4 = lane >> 4;

    __shared__ u16 Al[2 * 128 * 64];       // 32 KB
    __shared__ u16 Bl[2 * 256 * 64];       // 64 KB

    unsigned kslb = ((unsigned)((lane & 7) ^ (lane >> 3))) * 16u;
    unsigned aoff[2], boff[4];
    #pragma unroll
    for (int i = 0; i < 2; ++i) {
        int row = (wid * 2 + i) * 8 + (lane >> 3);   // 8*2*8 = 128 rows
        aoff[i] = (unsigned)(bm * 128 + row) * (unsigned)(K * 2) + kslb;
    }
    #pragma unroll
    for (int i = 0; i < 4; ++i) {
        int row = (wid * 4 + i) * 8 + (lane >> 3);   // 8*4*8 = 256 rows
        boff[i] = ((unsigned)e * (unsigned)N + (unsigned)(bn * 256 + row)) * (unsigned)(K * 2) + kslb;
    }

    f32x4 acc[4][4];
    #pragma unroll
    for (int m = 0; m < 4; ++m)
        #pragma unroll
        for (int n = 0; n < 4; ++n) acc[m][n] = f32x4{0.f, 0.f, 0.f, 0.f};

    auto stage = [&](int buf, int kt) {
        unsigned ko = (unsigned)kt * 128u;
        #pragma unroll
        for (int i = 0; i < 2; ++i)
            __builtin_amdgcn_global_load_lds(GLB((const char*)Asrc + aoff[i] + ko),
                LDSP(&Al[buf * 8192 + (wid * 2 + i) * 512]), 16, 0, 0);
        #pragma unroll
        for (int i = 0; i < 4; ++i)
            __builtin_amdgcn_global_load_lds(GLB((const char*)Bw + boff[i] + ko),
                LDSP(&Bl[buf * 16384 + (wid * 4 + i) * 512]), 16, 0, 0);
    };

    auto compute = [&](int buf) {
        const char* Ab = (const char*)&Al[buf * 8192];
        const char* Bb = (const char*)&Bl[buf * 16384];
        #pragma unroll
        for (int s = 0; s < 2; ++s) {
            unsigned sl = (unsigned)((((s * 4) + l4) ^ (lane & 7)) << 4);
            bf16x8 af[4], bfr[4];
            #pragma unroll
            for (int m = 0; m < 4; ++m)
                af[m] = *(const bf16x8*)(Ab + (unsigned)(wr * 64 + m * 16 + l15) * 128u + sl);
            #pragma unroll
            for (int n = 0; n < 4; ++n)
                bfr[n] = *(const bf16x8*)(Bb + (unsigned)(wc * 64 + n * 16 + l15) * 128u + sl);
            __builtin_amdgcn_s_setprio(1);
            #pragma unroll
            for (int m = 0; m < 4; ++m)
                #pragma unroll
                for (int n = 0; n < 4; ++n)
                    acc[m][n] = __builtin_amdgcn_mfma_f32_16x16x32_bf16(af[m], bfr[n], acc[m][n], 0, 0, 0);
            __builtin_amdgcn_s_setprio(0);
        }
    };

    stage(0, 0);
    asm volatile("s_waitcnt vmcnt(0)" ::: "memory");
    __syncthreads();
    int cur = 0;
    const int NT = K / 64;
    for (int kt = 1; kt < NT; ++kt) {
        stage(cur ^ 1, kt);
        compute(cur);
        asm volatile("s_waitcnt vmcnt(0)" ::: "memory");
        __syncthreads();
        cur ^= 1;
    }
    compute(cur);

    int rb = bm * 128 + wr * 64 + l4 * 4;
    int cb = bn * 256 + wc * 64 + l15;
    #pragma unroll
    for (int n = 0; n < 4; ++n) {
        int col = cb + n * 16;
        float bv = bias[e * N + col];
        #pragma unroll
        for (int m = 0; m < 4; ++m) {
            #pragma unroll
            for (int r = 0; r < 4; ++r) {
                int row = rb + m * 16 + r;
                float v = acc[m][n][r] + bv;
                Out[(size_t)row * N + col] = f2bf(v);
            }
        }
    }
}

// ---------- 7: combine — 2 tokens/block, bf16 ybuf reads, f32 out ----------
__global__ __launch_bounds__(256) void k_combine(const u16* __restrict__ ybuf,
        const int* __restrict__ token_rows, const float* __restrict__ row_weight,
        float* __restrict__ out) {
    int t = blockIdx.x * 2 + (threadIdx.x >> 7);
    int d = (threadIdx.x & 127) * 8;
    int r0 = token_rows[2*t], r1 = token_rows[2*t+1];
    float w0 = row_weight[r0], w1 = row_weight[r1];
    uint4 a = *(const uint4*)&ybuf[(size_t)r0 * DM + d];
    uint4 b = *(const uint4*)&ybuf[(size_t)r1 * DM + d];
    unsigned ua[4] = {a.x, a.y, a.z, a.w}, ub[4] = {b.x, b.y, b.z, b.w};
    float res[8];
    #pragma unroll
    for (int i = 0; i < 4; ++i) {
        res[2*i]   = w0 * __uint_as_float((ua[i] & 0xffffu) << 16) + w1 * __uint_as_float((ub[i] & 0xffffu) << 16);
        res[2*i+1] = w0 * __uint_as_float(ua[i] & 0xffff0000u)     + w1 * __uint_as_float(ub[i] & 0xffff0000u);
    }
    float* o = &out[(size_t)t * DM + d];
    *(float4*)o       = make_float4(res[0], res[1], res[2], res[3]);
    *(float4*)(o + 4) = make_float4(res[4], res[5], res[6], res[7]);
}

extern "C" void kernel_launch(void* const* d_in, const int* in_sizes, int n_in,
                              void* d_out, int out_size, void* d_ws, size_t ws_size,
                              hipStream_t stream) {
    const float* x  = (const float*)d_in[0];
    const float* gw = (const float*)d_in[1];
    const float* gb = (const float*)d_in[2];
    const float* w1 = (const float*)d_in[3];
    const float* b1 = (const float*)d_in[4];
    const float* w2 = (const float*)d_in[5];
    const float* b2 = (const float*)d_in[6];
    float* out = (float*)d_out;

    char* ws = (char*)d_ws;
    size_t off = 0;
    auto alloc = [&](size_t bytes) -> void* {
        void* p = ws + off; off = (off + bytes + 255) & ~(size_t)255; return p;
    };
    // ybuf (written by GEMM2, bf16) aliases w1t, dead after GEMM1 (stream-ordered).
    u16*   w1t  = (u16*)alloc((size_t)NE * DM * HID * 2);   // 67.1 MB
    u16*   xb   = (u16*)alloc((size_t)T_TOK * DM * 2);      // 16.8 MB
    u16*   w2t  = (u16*)alloc((size_t)NE * DM * HID * 2);   // 67.1 MB
    u16*   hbuf = (u16*)alloc((size_t)RP2 * HID * 2);       // 151 MB
    int*   tok_e = (int*)alloc(2 * T_TOK * 4);
    float* tok_w = (float*)alloc(2 * T_TOK * 4);
    int*   counts  = (int*)alloc(64);
    int*   cursors = (int*)alloc(64);
    int*   pad_off = (int*)alloc(64);
    int*   row_token  = (int*)alloc(RP2 * 4);
    float* row_weight = (float*)alloc(RP2 * 4);
    int*   token_rows = (int*)alloc(2 * T_TOK * 4);
    int*   tile_expert = (int*)alloc(MT128 * 4);
    u16*   ybuf = w1t;                                      // 37.7 MB alias (bf16)

    k_init<<<RP2/256, 256, 0, stream>>>(counts, cursors, row_token);
    k_gate<<<T_TOK/4, 256, 0, stream>>>(x, gw, gb, tok_e, tok_w, counts, xb);
    k_scan<<<1, 256, 0, stream>>>(counts, pad_off, tile_expert);
    k_assign<<<T_TOK/256, 256, 0, stream>>>(tok_e, tok_w, pad_off, cursors, row_token, row_weight, token_rows);
    k_transpose<DM, HID><<<NE*(DM/256)*(HID/64), 256, 0, stream>>>(w1, w1t);
    k_transpose<HID, DM><<<NE*(HID/256)*(DM/64), 256, 0, stream>>>(w2, w2t);
    // GEMM1: 256x256 dbuf, grid 1152, chunked XCD swizzle
    k_gemm256<HID/256, HID, DM, true, true><<<(HID/256)*MT256, 512, 0, stream>>>(
        xb, w1t, b1, (void*)hbuf, row_token, tile_expert, MT256);
    // GEMM2: 128x256 dbuf, grid 576 (%8==0), chunked XCD swizzle, bf16 out
    k_gemm2<DM, HID><<<(DM/256)*MT128, 512, 0, stream>>>(
        hbuf, w2t, b2, ybuf, tile_expert, MT128);
    k_combine<<<T_TOK/2, 256, 0, stream>>>(ybuf, token_rows, row_weight, out);
}

// Round 15
// 872.063 us; speedup vs baseline: 1.0314x; 1.0314x over previous
//
#include <hip/hip_runtime.h>
#include <stdint.h>

#define T_TOK 8192
#define DM 1024
#define HID 4096
#define NE 8
#define RP2 18432      // 16384 + 8*256 worst-case rows padded to 256
#define MT128 144      // RP2 / 128
#define MT256 72       // RP2 / 256

typedef unsigned short u16;
typedef __attribute__((ext_vector_type(4))) float f32x4;
typedef __attribute__((ext_vector_type(8))) __bf16 bf16x8;

#define GLB(p) ((const __attribute__((address_space(1))) unsigned int*)(p))
#define LDSP(p) ((__attribute__((address_space(3))) unsigned int*)(p))

__device__ __forceinline__ u16 f2bf(float f) {
    union { float f; unsigned u; } c; c.f = f;
    unsigned r = (c.u + 0x7FFFu + ((c.u >> 16) & 1u)) >> 16;
    return (u16)r;
}

// ---------- 0: init counters + row_token ----------
__global__ __launch_bounds__(256) void k_init(int* counts, int* cursors, int* row_token) {
    int i = blockIdx.x * 256 + threadIdx.x;
    if (i < RP2) row_token[i] = -1;
    if (i < NE) { counts[i] = 0; cursors[i] = 0; }
}

// ---------- 1: gating (one wave per token, fp32) + fused x->bf16 convert ----------
__global__ __launch_bounds__(256) void k_gate(const float* __restrict__ x,
        const float* __restrict__ gw, const float* __restrict__ gb,
        int* __restrict__ tok_e, float* __restrict__ tok_w, int* __restrict__ counts,
        u16* __restrict__ xb) {
    int t = blockIdx.x * 4 + (threadIdx.x >> 6);
    int lane = threadIdx.x & 63;
    const float* xr = x + (size_t)t * DM;
    u16* xbr = xb + (size_t)t * DM;
    float a0=0,a1=0,a2=0,a3=0,a4=0,a5=0,a6=0,a7=0;
    for (int d = lane; d < DM; d += 64) {
        float xv = xr[d];
        xbr[d] = f2bf(xv);
        const float4* g = (const float4*)(gw + (size_t)d * NE);
        float4 g0 = g[0], g1 = g[1];
        a0 += xv*g0.x; a1 += xv*g0.y; a2 += xv*g0.z; a3 += xv*g0.w;
        a4 += xv*g1.x; a5 += xv*g1.y; a6 += xv*g1.z; a7 += xv*g1.w;
    }
    #pragma unroll
    for (int off = 32; off; off >>= 1) {
        a0 += __shfl_xor(a0, off); a1 += __shfl_xor(a1, off);
        a2 += __shfl_xor(a2, off); a3 += __shfl_xor(a3, off);
        a4 += __shfl_xor(a4, off); a5 += __shfl_xor(a5, off);
        a6 += __shfl_xor(a6, off); a7 += __shfl_xor(a7, off);
    }
    if (lane == 0) {
        float l[8] = {a0+gb[0],a1+gb[1],a2+gb[2],a3+gb[3],a4+gb[4],a5+gb[5],a6+gb[6],a7+gb[7]};
        int e0 = 0;
        #pragma unroll
        for (int e = 1; e < 8; ++e) if (l[e] > l[e0]) e0 = e;
        int e1 = (e0 == 0) ? 1 : 0;
        #pragma unroll
        for (int e = 0; e < 8; ++e) if (e != e0 && l[e] > l[e1]) e1 = e;
        float p1 = expf(l[e1] - l[e0]);
        float inv = 1.f / (1.f + p1);
        tok_e[2*t] = e0; tok_e[2*t+1] = e1;
        tok_w[2*t] = inv; tok_w[2*t+1] = p1 * inv;
        atomicAdd(&counts[e0], 1);
        atomicAdd(&counts[e1], 1);
    }
}

// ---------- 2: padded prefix (256-aligned) + tile->expert map (128-granular) ----------
__global__ void k_scan(const int* __restrict__ counts, int* __restrict__ pad_off,
                       int* __restrict__ tile_expert) {
    __shared__ int off[NE + 1];
    if (threadIdx.x == 0) {
        int o = 0;
        for (int e = 0; e < NE; ++e) { off[e] = o; pad_off[e] = o; o += ((counts[e] + 255) >> 8) << 8; }
        off[NE] = o; pad_off[NE] = o;
    }
    __syncthreads();
    for (int i = threadIdx.x; i < MT128; i += blockDim.x) {
        int ex = -1, base = i * 128;
        #pragma unroll
        for (int e = 0; e < NE; ++e) if (base >= off[e] && base < off[e+1]) ex = e;
        tile_expert[i] = ex;
    }
}

// ---------- 3: assign rows ----------
__global__ __launch_bounds__(256) void k_assign(const int* __restrict__ tok_e, const float* __restrict__ tok_w,
        const int* __restrict__ pad_off, int* __restrict__ cursors,
        int* __restrict__ row_token, float* __restrict__ row_weight, int* __restrict__ token_rows) {
    int t = blockIdx.x * 256 + threadIdx.x;
    if (t >= T_TOK) return;
    #pragma unroll
    for (int k = 0; k < 2; ++k) {
        int e = tok_e[2*t+k];
        int pos = atomicAdd(&cursors[e], 1);
        int r = pad_off[e] + pos;
        row_token[r] = t;
        row_weight[r] = tok_w[2*t+k];
        token_rows[2*t+k] = r;
    }
}

// ---------- 5: LDS-free register transpose: [E][R][C] f32 -> [E][C][R] bf16 ----------
template<int R, int C>
__global__ __launch_bounds__(256) void k_transpose(const float* __restrict__ in, u16* __restrict__ out) {
    const int TR = R / 128, TC = C / 64;
    const int tiles = TR * TC;
    int e = blockIdx.x / tiles;
    int rem = blockIdx.x % tiles;
    int rt = rem / TC, ct = rem % TC;
    const float* src = in + (size_t)e * R * C + (size_t)(rt * 128) * C + ct * 64;
    u16* dst = out + (size_t)e * R * C + (size_t)(ct * 64) * R + rt * 128;
    int t = threadIdx.x;
    int r8 = (t >> 4) * 8;
    int c4 = (t & 15) * 4;
    float4 v[8];
    #pragma unroll
    for (int j = 0; j < 8; ++j)
        v[j] = *(const float4*)&src[(size_t)(r8 + j) * C + c4];
    #pragma unroll
    for (int jj = 0; jj < 4; ++jj) {
        uint4 o;
        o.x = f2bf(((const float*)&v[0])[jj]) | ((unsigned)f2bf(((const float*)&v[1])[jj]) << 16);
        o.y = f2bf(((const float*)&v[2])[jj]) | ((unsigned)f2bf(((const float*)&v[3])[jj]) << 16);
        o.z = f2bf(((const float*)&v[4])[jj]) | ((unsigned)f2bf(((const float*)&v[5])[jj]) << 16);
        o.w = f2bf(((const float*)&v[6])[jj]) | ((unsigned)f2bf(((const float*)&v[7])[jj]) << 16);
        *(uint4*)&dst[(size_t)(c4 + jj) * R + r8] = o;
    }
}

// ---------- 6a: 256x256 8-wave double-buffered GEMM (GEMM1) — R3/R7-proven ----------
template<int NBN, int N, int K, bool GATHER, bool SILU>
__global__ __launch_bounds__(512, 2) void k_gemm256(
    const u16* __restrict__ Asrc, const u16* __restrict__ Bw,
    const float* __restrict__ bias, void* __restrict__ Out,
    const int* __restrict__ row_token, const int* __restrict__ tile_expert, int mt)
{
    int id = blockIdx.x;
    int cpx = (NBN * mt) >> 3;
    int sid = (id & 7) * cpx + (id >> 3);
    int bm = sid / NBN, bn = sid % NBN;
    int e = tile_expert[2 * bm];           // 256-pad => both 128-halves same expert
    if (e < 0) return;
    int tid = threadIdx.x, wid = tid >> 6, lane = tid & 63;
    int wr = wid >> 2, wc = wid & 3;

    __shared__ u16 Al[2 * 256 * 64];
    __shared__ u16 Bl[2 * 256 * 64];

    unsigned kslb = ((unsigned)((lane & 7) ^ (lane >> 3))) * 16u;
    unsigned aoff[4], boff[4];
    #pragma unroll
    for (int i = 0; i < 4; ++i) {
        int row = (wid * 4 + i) * 8 + (lane >> 3);
        unsigned arow;
        if (GATHER) {
            int tk = row_token[bm * 256 + row];
            if (tk < 0) tk = 0;            // pad rows: duplicate token 0 (ignored)
            arow = (unsigned)tk;
        } else {
            arow = (unsigned)(bm * 256 + row);
        }
        aoff[i] = arow * (unsigned)(K * 2) + kslb;
        boff[i] = ((unsigned)e * (unsigned)N + (unsigned)(bn * 256 + row)) * (unsigned)(K * 2) + kslb;
    }

    f32x4 acc[8][4];
    #pragma unroll
    for (int m = 0; m < 8; ++m)
        #pragma unroll
        for (int n = 0; n < 4; ++n) acc[m][n] = f32x4{0.f, 0.f, 0.f, 0.f};

    auto stage = [&](int buf, int kt) {
        unsigned ko = (unsigned)kt * 128u;
        #pragma unroll
        for (int i = 0; i < 4; ++i) {
            __builtin_amdgcn_global_load_lds(GLB((const char*)Asrc + aoff[i] + ko),
                LDSP(&Al[buf * 16384 + (wid * 4 + i) * 512]), 16, 0, 0);
            __builtin_amdgcn_global_load_lds(GLB((const char*)Bw + boff[i] + ko),
                LDSP(&Bl[buf * 16384 + (wid * 4 + i) * 512]), 16, 0, 0);
        }
    };

    auto compute = [&](int buf) {
        const char* Ab = (const char*)&Al[buf * 16384];
        const char* Bb = (const char*)&Bl[buf * 16384];
        unsigned sl0 = (unsigned)(((lane >> 4) ^ (lane & 7)) << 4);
        unsigned sl1 = (unsigned)((((lane >> 4) + 4) ^ (lane & 7)) << 4);
        bf16x8 bfr[4][2];
        #pragma unroll
        for (int n = 0; n < 4; ++n) {
            unsigned br = (unsigned)(wc * 64 + n * 16 + (lane & 15)) * 128u;
            bfr[n][0] = *(const bf16x8*)(Bb + br + sl0);
            bfr[n][1] = *(const bf16x8*)(Bb + br + sl1);
        }
        __builtin_amdgcn_s_setprio(1);
        #pragma unroll
        for (int m = 0; m < 8; ++m) {
            unsigned ar = (unsigned)(wr * 128 + m * 16 + (lane & 15)) * 128u;
            bf16x8 a0 = *(const bf16x8*)(Ab + ar + sl0);
            bf16x8 a1 = *(const bf16x8*)(Ab + ar + sl1);
            #pragma unroll
            for (int n = 0; n < 4; ++n) {
                acc[m][n] = __builtin_amdgcn_mfma_f32_16x16x32_bf16(a0, bfr[n][0], acc[m][n], 0, 0, 0);
                acc[m][n] = __builtin_amdgcn_mfma_f32_16x16x32_bf16(a1, bfr[n][1], acc[m][n], 0, 0, 0);
            }
        }
        __builtin_amdgcn_s_setprio(0);
    };

    stage(0, 0);
    asm volatile("s_waitcnt vmcnt(0)" ::: "memory");
    __syncthreads();
    int cur = 0;
    const int NT = K / 64;
    for (int kt = 1; kt < NT; ++kt) {
        stage(cur ^ 1, kt);
        compute(cur);
        asm volatile("s_waitcnt vmcnt(0)" ::: "memory");
        __syncthreads();
        cur ^= 1;
    }
    compute(cur);

    int rb = bm * 256 + wr * 128 + (lane >> 4) * 4;
    int cb = bn * 256 + wc * 64 + (lane & 15);
    #pragma unroll
    for (int n = 0; n < 4; ++n) {
        int col = cb + n * 16;
        float bv = bias[e * N + col];
        #pragma unroll
        for (int m = 0; m < 8; ++m) {
            #pragma unroll
            for (int r = 0; r < 4; ++r) {
                int row = rb + m * 16 + r;
                float v = acc[m][n][r] + bv;
                if (SILU) v = v / (1.f + __expf(-v));
                ((u16*)Out)[(size_t)row * N + col] = f2bf(v);
            }
        }
    }
}

// ---------- 6b: 128x128 4-wave GEMM (GEMM2) — R3-proven, bf16 out ----------
template<int NBN, int N, int K, bool GATHER, bool SILU>
__global__ __launch_bounds__(256) void k_gemm128(
    const u16* __restrict__ Asrc, const u16* __restrict__ Bw,
    const float* __restrict__ bias, void* __restrict__ Out,
    const int* __restrict__ row_token, const int* __restrict__ tile_expert, int mt)
{
    int id = blockIdx.x;
    int cpx = (NBN * mt) >> 3;
    int sid = (id & 7) * cpx + (id >> 3);
    int bm = sid / NBN;
    int bn = sid % NBN;

    int e = tile_expert[bm];
    if (e < 0) return;
    int tid = threadIdx.x, wid = tid >> 6, lane = tid & 63;

    __shared__ u16 Al[128 * 64];
    __shared__ u16 Bl[128 * 64];

    const u16* ap[4];
    const u16* bp[4];
    int ksl = ((lane & 7) ^ (lane >> 3)) * 8;
    #pragma unroll
    for (int i = 0; i < 4; ++i) {
        int row = (wid * 4 + i) * 8 + (lane >> 3);
        size_t arow;
        if (GATHER) {
            int tk = row_token[bm * 128 + row];
            if (tk < 0) tk = 0;
            arow = (size_t)tk * K;
        } else {
            arow = (size_t)(bm * 128 + row) * K;
        }
        ap[i] = Asrc + arow + ksl;
        bp[i] = Bw + (size_t)e * N * K + (size_t)(bn * 128 + row) * K + ksl;
    }

    f32x4 acc[4][4];
    #pragma unroll
    for (int i = 0; i < 4; ++i)
        #pragma unroll
        for (int j = 0; j < 4; ++j) acc[i][j] = f32x4{0.f, 0.f, 0.f, 0.f};

    int wr = wid >> 1, wc = wid & 1;

    for (int kt = 0; kt < K / 64; ++kt) {
        #pragma unroll
        for (int i = 0; i < 4; ++i) {
            __builtin_amdgcn_global_load_lds(GLB(ap[i] + kt * 64), LDSP(&Al[(wid*4+i)*512]), 16, 0, 0);
            __builtin_amdgcn_global_load_lds(GLB(bp[i] + kt * 64), LDSP(&Bl[(wid*4+i)*512]), 16, 0, 0);
        }
        asm volatile("s_waitcnt vmcnt(0)" ::: "memory");
        __syncthreads();
        #pragma unroll
        for (int s = 0; s < 2; ++s) {
            int sl = (((s * 4) + (lane >> 4)) ^ (lane & 7)) << 4;
            bf16x8 af[4], bfr[4];
            #pragma unroll
            for (int i = 0; i < 4; ++i) {
                int ar = wr * 64 + i * 16 + (lane & 15);
                af[i] = *(const bf16x8*)((const char*)Al + ar * 128 + sl);
            }
            #pragma unroll
            for (int j = 0; j < 4; ++j) {
                int br = wc * 64 + j * 16 + (lane & 15);
                bfr[j] = *(const bf16x8*)((const char*)Bl + br * 128 + sl);
            }
            #pragma unroll
            for (int i = 0; i < 4; ++i)
                #pragma unroll
                for (int j = 0; j < 4; ++j)
                    acc[i][j] = __builtin_amdgcn_mfma_f32_16x16x32_bf16(af[i], bfr[j], acc[i][j], 0, 0, 0);
        }
        __syncthreads();
    }

    int rbase = bm * 128 + wr * 64 + (lane >> 4) * 4;
    int cbase = bn * 128 + wc * 64 + (lane & 15);
    #pragma unroll
    for (int j = 0; j < 4; ++j) {
        int col = cbase + j * 16;
        float bv = bias[e * N + col];
        #pragma unroll
        for (int i = 0; i < 4; ++i) {
            #pragma unroll
            for (int r = 0; r < 4; ++r) {
                int row = rbase + i * 16 + r;
                float v = acc[i][j][r] + bv;
                if (SILU) v = v / (1.f + __expf(-v));
                ((u16*)Out)[(size_t)row * N + col] = f2bf(v);
            }
        }
    }
}

// ---------- 7: combine — 2 tokens/block, bf16 ybuf reads, f32 out ----------
__global__ __launch_bounds__(256) void k_combine(const u16* __restrict__ ybuf,
        const int* __restrict__ token_rows, const float* __restrict__ row_weight,
        float* __restrict__ out) {
    int t = blockIdx.x * 2 + (threadIdx.x >> 7);
    int d = (threadIdx.x & 127) * 8;
    int r0 = token_rows[2*t], r1 = token_rows[2*t+1];
    float w0 = row_weight[r0], w1 = row_weight[r1];
    uint4 a = *(const uint4*)&ybuf[(size_t)r0 * DM + d];
    uint4 b = *(const uint4*)&ybuf[(size_t)r1 * DM + d];
    unsigned ua[4] = {a.x, a.y, a.z, a.w}, ub[4] = {b.x, b.y, b.z, b.w};
    float res[8];
    #pragma unroll
    for (int i = 0; i < 4; ++i) {
        res[2*i]   = w0 * __uint_as_float((ua[i] & 0xffffu) << 16) + w1 * __uint_as_float((ub[i] & 0xffffu) << 16);
        res[2*i+1] = w0 * __uint_as_float(ua[i] & 0xffff0000u)     + w1 * __uint_as_float(ub[i] & 0xffff0000u);
    }
    float* o = &out[(size_t)t * DM + d];
    *(float4*)o       = make_float4(res[0], res[1], res[2], res[3]);
    *(float4*)(o + 4) = make_float4(res[4], res[5], res[6], res[7]);
}

extern "C" void kernel_launch(void* const* d_in, const int* in_sizes, int n_in,
                              void* d_out, int out_size, void* d_ws, size_t ws_size,
                              hipStream_t stream) {
    const float* x  = (const float*)d_in[0];
    const float* gw = (const float*)d_in[1];
    const float* gb = (const float*)d_in[2];
    const float* w1 = (const float*)d_in[3];
    const float* b1 = (const float*)d_in[4];
    const float* w2 = (const float*)d_in[5];
    const float* b2 = (const float*)d_in[6];
    float* out = (float*)d_out;

    char* ws = (char*)d_ws;
    size_t off = 0;
    auto alloc = [&](size_t bytes) -> void* {
        void* p = ws + off; off = (off + bytes + 255) & ~(size_t)255; return p;
    };
    // ybuf (written by GEMM2, bf16) aliases w1t, dead after GEMM1 (stream-ordered).
    u16*   w1t  = (u16*)alloc((size_t)NE * DM * HID * 2);   // 67.1 MB
    u16*   xb   = (u16*)alloc((size_t)T_TOK * DM * 2);      // 16.8 MB
    u16*   w2t  = (u16*)alloc((size_t)NE * DM * HID * 2);   // 67.1 MB
    u16*   hbuf = (u16*)alloc((size_t)RP2 * HID * 2);       // 151 MB
    int*   tok_e = (int*)alloc(2 * T_TOK * 4);
    float* tok_w = (float*)alloc(2 * T_TOK * 4);
    int*   counts  = (int*)alloc(64);
    int*   cursors = (int*)alloc(64);
    int*   pad_off = (int*)alloc(64);
    int*   row_token  = (int*)alloc(RP2 * 4);
    float* row_weight = (float*)alloc(RP2 * 4);
    int*   token_rows = (int*)alloc(2 * T_TOK * 4);
    int*   tile_expert = (int*)alloc(MT128 * 4);
    u16*   ybuf = w1t;                                      // 37.7 MB alias (bf16)

    k_init<<<RP2/256, 256, 0, stream>>>(counts, cursors, row_token);
    k_gate<<<T_TOK/4, 256, 0, stream>>>(x, gw, gb, tok_e, tok_w, counts, xb);
    k_scan<<<1, 256, 0, stream>>>(counts, pad_off, tile_expert);
    k_assign<<<T_TOK/256, 256, 0, stream>>>(tok_e, tok_w, pad_off, cursors, row_token, row_weight, token_rows);
    k_transpose<DM, HID><<<NE*(DM/128)*(HID/64), 256, 0, stream>>>(w1, w1t);
    k_transpose<HID, DM><<<NE*(HID/128)*(DM/64), 256, 0, stream>>>(w2, w2t);
    // GEMM1: 256x256 dbuf, grid 1152 (%8==0), chunked XCD swizzle
    k_gemm256<HID/256, HID, DM, true, true><<<(HID/256)*MT256, 512, 0, stream>>>(
        xb, w1t, b1, (void*)hbuf, row_token, tile_expert, MT256);
    // GEMM2: 128x128, grid 1152 (%8==0), chunked XCD swizzle, bf16 out
    k_gemm128<DM/128, DM, HID, false, false><<<(DM/128)*MT128, 256, 0, stream>>>(
        hbuf, w2t, b2, (void*)ybuf, row_token, tile_expert, MT128);
    k_combine<<<T_TOK/2, 256, 0, stream>>>(ybuf, token_rows, row_weight, out);
}

// Round 16
// 870.129 us; speedup vs baseline: 1.0337x; 1.0022x over previous
//
#include <hip/hip_runtime.h>
#include <stdint.h>

#define T_TOK 8192
#define DM 1024
#define HID 4096
#define NE 8
#define RP2 18432      // 16384 + 8*256 worst-case rows padded to 256
#define MT128 144      // RP2 / 128
#define MT256 72       // RP2 / 256

typedef unsigned short u16;
typedef __attribute__((ext_vector_type(4))) float f32x4;
typedef __attribute__((ext_vector_type(8))) __bf16 bf16x8;

#define GLB(p) ((const __attribute__((address_space(1))) unsigned int*)(p))
#define LDSP(p) ((__attribute__((address_space(3))) unsigned int*)(p))

__device__ __forceinline__ u16 f2bf(float f) {
    union { float f; unsigned u; } c; c.f = f;
    unsigned r = (c.u + 0x7FFFu + ((c.u >> 16) & 1u)) >> 16;
    return (u16)r;
}

// ---------- 0: init counters + row_token ----------
__global__ __launch_bounds__(256) void k_init(int* counts, int* cursors, int* row_token) {
    int i = blockIdx.x * 256 + threadIdx.x;
    if (i < RP2) row_token[i] = -1;
    if (i < NE) { counts[i] = 0; cursors[i] = 0; }
}

// ---------- 1: gating (one wave per token) + fused x->bf16 convert, float4-vectorized ----------
__global__ __launch_bounds__(256) void k_gate(const float* __restrict__ x,
        const float* __restrict__ gw, const float* __restrict__ gb,
        int* __restrict__ tok_e, float* __restrict__ tok_w, int* __restrict__ counts,
        u16* __restrict__ xb) {
    int t = blockIdx.x * 4 + (threadIdx.x >> 6);
    int lane = threadIdx.x & 63;
    const float4* xr = (const float4*)(x + (size_t)t * DM);
    u16* xbr = xb + (size_t)t * DM;
    float a0=0,a1=0,a2=0,a3=0,a4=0,a5=0,a6=0,a7=0;
    #pragma unroll
    for (int it = 0; it < DM / 256; ++it) {
        int d4 = it * 64 + lane;                 // float4 index 0..255
        float4 v = xr[d4];
        ushort4 o;
        o.x = f2bf(v.x); o.y = f2bf(v.y); o.z = f2bf(v.z); o.w = f2bf(v.w);
        *(ushort4*)&xbr[d4 * 4] = o;             // 8B coalesced bf16 write
        const float xs[4] = {v.x, v.y, v.z, v.w};
        #pragma unroll
        for (int j = 0; j < 4; ++j) {
            float xv = xs[j];
            const float4* g = (const float4*)(gw + (size_t)(d4 * 4 + j) * NE);
            float4 g0 = g[0], g1 = g[1];
            a0 += xv*g0.x; a1 += xv*g0.y; a2 += xv*g0.z; a3 += xv*g0.w;
            a4 += xv*g1.x; a5 += xv*g1.y; a6 += xv*g1.z; a7 += xv*g1.w;
        }
    }
    #pragma unroll
    for (int off = 32; off; off >>= 1) {
        a0 += __shfl_xor(a0, off); a1 += __shfl_xor(a1, off);
        a2 += __shfl_xor(a2, off); a3 += __shfl_xor(a3, off);
        a4 += __shfl_xor(a4, off); a5 += __shfl_xor(a5, off);
        a6 += __shfl_xor(a6, off); a7 += __shfl_xor(a7, off);
    }
    if (lane == 0) {
        float l[8] = {a0+gb[0],a1+gb[1],a2+gb[2],a3+gb[3],a4+gb[4],a5+gb[5],a6+gb[6],a7+gb[7]};
        int e0 = 0;
        #pragma unroll
        for (int e = 1; e < 8; ++e) if (l[e] > l[e0]) e0 = e;
        int e1 = (e0 == 0) ? 1 : 0;
        #pragma unroll
        for (int e = 0; e < 8; ++e) if (e != e0 && l[e] > l[e1]) e1 = e;
        float p1 = expf(l[e1] - l[e0]);
        float inv = 1.f / (1.f + p1);
        tok_e[2*t] = e0; tok_e[2*t+1] = e1;
        tok_w[2*t] = inv; tok_w[2*t+1] = p1 * inv;
        atomicAdd(&counts[e0], 1);
        atomicAdd(&counts[e1], 1);
    }
}

// ---------- 2: padded prefix (256-aligned) + tile->expert map (128-granular) ----------
__global__ void k_scan(const int* __restrict__ counts, int* __restrict__ pad_off,
                       int* __restrict__ tile_expert) {
    __shared__ int off[NE + 1];
    if (threadIdx.x == 0) {
        int o = 0;
        for (int e = 0; e < NE; ++e) { off[e] = o; pad_off[e] = o; o += ((counts[e] + 255) >> 8) << 8; }
        off[NE] = o; pad_off[NE] = o;
    }
    __syncthreads();
    for (int i = threadIdx.x; i < MT128; i += blockDim.x) {
        int ex = -1, base = i * 128;
        #pragma unroll
        for (int e = 0; e < NE; ++e) if (base >= off[e] && base < off[e+1]) ex = e;
        tile_expert[i] = ex;
    }
}

// ---------- 3: assign rows ----------
__global__ __launch_bounds__(256) void k_assign(const int* __restrict__ tok_e, const float* __restrict__ tok_w,
        const int* __restrict__ pad_off, int* __restrict__ cursors,
        int* __restrict__ row_token, float* __restrict__ row_weight, int* __restrict__ token_rows) {
    int t = blockIdx.x * 256 + threadIdx.x;
    if (t >= T_TOK) return;
    #pragma unroll
    for (int k = 0; k < 2; ++k) {
        int e = tok_e[2*t+k];
        int pos = atomicAdd(&cursors[e], 1);
        int r = pad_off[e] + pos;
        row_token[r] = t;
        row_weight[r] = tok_w[2*t+k];
        token_rows[2*t+k] = r;
    }
}

// ---------- 5: LDS-free register transpose: [E][R][C] f32 -> [E][C][R] bf16 ----------
template<int R, int C>
__global__ __launch_bounds__(256) void k_transpose(const float* __restrict__ in, u16* __restrict__ out) {
    const int TR = R / 128, TC = C / 64;
    const int tiles = TR * TC;
    int e = blockIdx.x / tiles;
    int rem = blockIdx.x % tiles;
    int rt = rem / TC, ct = rem % TC;
    const float* src = in + (size_t)e * R * C + (size_t)(rt * 128) * C + ct * 64;
    u16* dst = out + (size_t)e * R * C + (size_t)(ct * 64) * R + rt * 128;
    int t = threadIdx.x;
    int r8 = (t >> 4) * 8;
    int c4 = (t & 15) * 4;
    float4 v[8];
    #pragma unroll
    for (int j = 0; j < 8; ++j)
        v[j] = *(const float4*)&src[(size_t)(r8 + j) * C + c4];
    #pragma unroll
    for (int jj = 0; jj < 4; ++jj) {
        uint4 o;
        o.x = f2bf(((const float*)&v[0])[jj]) | ((unsigned)f2bf(((const float*)&v[1])[jj]) << 16);
        o.y = f2bf(((const float*)&v[2])[jj]) | ((unsigned)f2bf(((const float*)&v[3])[jj]) << 16);
        o.z = f2bf(((const float*)&v[4])[jj]) | ((unsigned)f2bf(((const float*)&v[5])[jj]) << 16);
        o.w = f2bf(((const float*)&v[6])[jj]) | ((unsigned)f2bf(((const float*)&v[7])[jj]) << 16);
        *(uint4*)&dst[(size_t)(c4 + jj) * R + r8] = o;
    }
}

// ---------- 6a: 256x256 8-wave double-buffered GEMM (GEMM1) — R3/R7-proven ----------
template<int NBN, int N, int K, bool GATHER, bool SILU>
__global__ __launch_bounds__(512, 2) void k_gemm256(
    const u16* __restrict__ Asrc, const u16* __restrict__ Bw,
    const float* __restrict__ bias, void* __restrict__ Out,
    const int* __restrict__ row_token, const int* __restrict__ tile_expert, int mt)
{
    int id = blockIdx.x;
    int cpx = (NBN * mt) >> 3;
    int sid = (id & 7) * cpx + (id >> 3);
    int bm = sid / NBN, bn = sid % NBN;
    int e = tile_expert[2 * bm];           // 256-pad => both 128-halves same expert
    if (e < 0) return;
    int tid = threadIdx.x, wid = tid >> 6, lane = tid & 63;
    int wr = wid >> 2, wc = wid & 3;

    __shared__ u16 Al[2 * 256 * 64];
    __shared__ u16 Bl[2 * 256 * 64];

    unsigned kslb = ((unsigned)((lane & 7) ^ (lane >> 3))) * 16u;
    unsigned aoff[4], boff[4];
    #pragma unroll
    for (int i = 0; i < 4; ++i) {
        int row = (wid * 4 + i) * 8 + (lane >> 3);
        unsigned arow;
        if (GATHER) {
            int tk = row_token[bm * 256 + row];
            if (tk < 0) tk = 0;            // pad rows: duplicate token 0 (ignored)
            arow = (unsigned)tk;
        } else {
            arow = (unsigned)(bm * 256 + row);
        }
        aoff[i] = arow * (unsigned)(K * 2) + kslb;
        boff[i] = ((unsigned)e * (unsigned)N + (unsigned)(bn * 256 + row)) * (unsigned)(K * 2) + kslb;
    }

    f32x4 acc[8][4];
    #pragma unroll
    for (int m = 0; m < 8; ++m)
        #pragma unroll
        for (int n = 0; n < 4; ++n) acc[m][n] = f32x4{0.f, 0.f, 0.f, 0.f};

    auto stage = [&](int buf, int kt) {
        unsigned ko = (unsigned)kt * 128u;
        #pragma unroll
        for (int i = 0; i < 4; ++i) {
            __builtin_amdgcn_global_load_lds(GLB((const char*)Asrc + aoff[i] + ko),
                LDSP(&Al[buf * 16384 + (wid * 4 + i) * 512]), 16, 0, 0);
            __builtin_amdgcn_global_load_lds(GLB((const char*)Bw + boff[i] + ko),
                LDSP(&Bl[buf * 16384 + (wid * 4 + i) * 512]), 16, 0, 0);
        }
    };

    auto compute = [&](int buf) {
        const char* Ab = (const char*)&Al[buf * 16384];
        const char* Bb = (const char*)&Bl[buf * 16384];
        unsigned sl0 = (unsigned)(((lane >> 4) ^ (lane & 7)) << 4);
        unsigned sl1 = (unsigned)((((lane >> 4) + 4) ^ (lane & 7)) << 4);
        bf16x8 bfr[4][2];
        #pragma unroll
        for (int n = 0; n < 4; ++n) {
            unsigned br = (unsigned)(wc * 64 + n * 16 + (lane & 15)) * 128u;
            bfr[n][0] = *(const bf16x8*)(Bb + br + sl0);
            bfr[n][1] = *(const bf16x8*)(Bb + br + sl1);
        }
        __builtin_amdgcn_s_setprio(1);
        #pragma unroll
        for (int m = 0; m < 8; ++m) {
            unsigned ar = (unsigned)(wr * 128 + m * 16 + (lane & 15)) * 128u;
            bf16x8 a0 = *(const bf16x8*)(Ab + ar + sl0);
            bf16x8 a1 = *(const bf16x8*)(Ab + ar + sl1);
            #pragma unroll
            for (int n = 0; n < 4; ++n) {
                acc[m][n] = __builtin_amdgcn_mfma_f32_16x16x32_bf16(a0, bfr[n][0], acc[m][n], 0, 0, 0);
                acc[m][n] = __builtin_amdgcn_mfma_f32_16x16x32_bf16(a1, bfr[n][1], acc[m][n], 0, 0, 0);
            }
        }
        __builtin_amdgcn_s_setprio(0);
    };

    stage(0, 0);
    asm volatile("s_waitcnt vmcnt(0)" ::: "memory");
    __syncthreads();
    int cur = 0;
    const int NT = K / 64;
    for (int kt = 1; kt < NT; ++kt) {
        stage(cur ^ 1, kt);
        compute(cur);
        asm volatile("s_waitcnt vmcnt(0)" ::: "memory");
        __syncthreads();
        cur ^= 1;
    }
    compute(cur);

    int rb = bm * 256 + wr * 128 + (lane >> 4) * 4;
    int cb = bn * 256 + wc * 64 + (lane & 15);
    #pragma unroll
    for (int n = 0; n < 4; ++n) {
        int col = cb + n * 16;
        float bv = bias[e * N + col];
        #pragma unroll
        for (int m = 0; m < 8; ++m) {
            #pragma unroll
            for (int r = 0; r < 4; ++r) {
                int row = rb + m * 16 + r;
                float v = acc[m][n][r] + bv;
                if (SILU) v = v / (1.f + __expf(-v));
                ((u16*)Out)[(size_t)row * N + col] = f2bf(v);
            }
        }
    }
}

// ---------- 6b: 128x128 4-wave GEMM (GEMM2) — R3-proven, bf16 out ----------
template<int NBN, int N, int K, bool GATHER, bool SILU>
__global__ __launch_bounds__(256) void k_gemm128(
    const u16* __restrict__ Asrc, const u16* __restrict__ Bw,
    const float* __restrict__ bias, void* __restrict__ Out,
    const int* __restrict__ row_token, const int* __restrict__ tile_expert, int mt)
{
    int id = blockIdx.x;
    int cpx = (NBN * mt) >> 3;
    int sid = (id & 7) * cpx + (id >> 3);
    int bm = sid / NBN;
    int bn = sid % NBN;

    int e = tile_expert[bm];
    if (e < 0) return;
    int tid = threadIdx.x, wid = tid >> 6, lane = tid & 63;

    __shared__ u16 Al[128 * 64];
    __shared__ u16 Bl[128 * 64];

    const u16* ap[4];
    const u16* bp[4];
    int ksl = ((lane & 7) ^ (lane >> 3)) * 8;
    #pragma unroll
    for (int i = 0; i < 4; ++i) {
        int row = (wid * 4 + i) * 8 + (lane >> 3);
        size_t arow;
        if (GATHER) {
            int tk = row_token[bm * 128 + row];
            if (tk < 0) tk = 0;
            arow = (size_t)tk * K;
        } else {
            arow = (size_t)(bm * 128 + row) * K;
        }
        ap[i] = Asrc + arow + ksl;
        bp[i] = Bw + (size_t)e * N * K + (size_t)(bn * 128 + row) * K + ksl;
    }

    f32x4 acc[4][4];
    #pragma unroll
    for (int i = 0; i < 4; ++i)
        #pragma unroll
        for (int j = 0; j < 4; ++j) acc[i][j] = f32x4{0.f, 0.f, 0.f, 0.f};

    int wr = wid >> 1, wc = wid & 1;

    for (int kt = 0; kt < K / 64; ++kt) {
        #pragma unroll
        for (int i = 0; i < 4; ++i) {
            __builtin_amdgcn_global_load_lds(GLB(ap[i] + kt * 64), LDSP(&Al[(wid*4+i)*512]), 16, 0, 0);
            __builtin_amdgcn_global_load_lds(GLB(bp[i] + kt * 64), LDSP(&Bl[(wid*4+i)*512]), 16, 0, 0);
        }
        asm volatile("s_waitcnt vmcnt(0)" ::: "memory");
        __syncthreads();
        #pragma unroll
        for (int s = 0; s < 2; ++s) {
            int sl = (((s * 4) + (lane >> 4)) ^ (lane & 7)) << 4;
            bf16x8 af[4], bfr[4];
            #pragma unroll
            for (int i = 0; i < 4; ++i) {
                int ar = wr * 64 + i * 16 + (lane & 15);
                af[i] = *(const bf16x8*)((const char*)Al + ar * 128 + sl);
            }
            #pragma unroll
            for (int j = 0; j < 4; ++j) {
                int br = wc * 64 + j * 16 + (lane & 15);
                bfr[j] = *(const bf16x8*)((const char*)Bl + br * 128 + sl);
            }
            #pragma unroll
            for (int i = 0; i < 4; ++i)
                #pragma unroll
                for (int j = 0; j < 4; ++j)
                    acc[i][j] = __builtin_amdgcn_mfma_f32_16x16x32_bf16(af[i], bfr[j], acc[i][j], 0, 0, 0);
        }
        __syncthreads();
    }

    int rbase = bm * 128 + wr * 64 + (lane >> 4) * 4;
    int cbase = bn * 128 + wc * 64 + (lane & 15);
    #pragma unroll
    for (int j = 0; j < 4; ++j) {
        int col = cbase + j * 16;
        float bv = bias[e * N + col];
        #pragma unroll
        for (int i = 0; i < 4; ++i) {
            #pragma unroll
            for (int r = 0; r < 4; ++r) {
                int row = rbase + i * 16 + r;
                float v = acc[i][j][r] + bv;
                if (SILU) v = v / (1.f + __expf(-v));
                ((u16*)Out)[(size_t)row * N + col] = f2bf(v);
            }
        }
    }
}

// ---------- 7: combine — 2 tokens/block, bf16 ybuf reads, f32 out ----------
__global__ __launch_bounds__(256) void k_combine(const u16* __restrict__ ybuf,
        const int* __restrict__ token_rows, const float* __restrict__ row_weight,
        float* __restrict__ out) {
    int t = blockIdx.x * 2 + (threadIdx.x >> 7);
    int d = (threadIdx.x & 127) * 8;
    int r0 = token_rows[2*t], r1 = token_rows[2*t+1];
    float w0 = row_weight[r0], w1 = row_weight[r1];
    uint4 a = *(const uint4*)&ybuf[(size_t)r0 * DM + d];
    uint4 b = *(const uint4*)&ybuf[(size_t)r1 * DM + d];
    unsigned ua[4] = {a.x, a.y, a.z, a.w}, ub[4] = {b.x, b.y, b.z, b.w};
    float res[8];
    #pragma unroll
    for (int i = 0; i < 4; ++i) {
        res[2*i]   = w0 * __uint_as_float((ua[i] & 0xffffu) << 16) + w1 * __uint_as_float((ub[i] & 0xffffu) << 16);
        res[2*i+1] = w0 * __uint_as_float(ua[i] & 0xffff0000u)     + w1 * __uint_as_float(ub[i] & 0xffff0000u);
    }
    float* o = &out[(size_t)t * DM + d];
    *(float4*)o       = make_float4(res[0], res[1], res[2], res[3]);
    *(float4*)(o + 4) = make_float4(res[4], res[5], res[6], res[7]);
}

extern "C" void kernel_launch(void* const* d_in, const int* in_sizes, int n_in,
                              void* d_out, int out_size, void* d_ws, size_t ws_size,
                              hipStream_t stream) {
    const float* x  = (const float*)d_in[0];
    const float* gw = (const float*)d_in[1];
    const float* gb = (const float*)d_in[2];
    const float* w1 = (const float*)d_in[3];
    const float* b1 = (const float*)d_in[4];
    const float* w2 = (const float*)d_in[5];
    const float* b2 = (const float*)d_in[6];
    float* out = (float*)d_out;

    char* ws = (char*)d_ws;
    size_t off = 0;
    auto alloc = [&](size_t bytes) -> void* {
        void* p = ws + off; off = (off + bytes + 255) & ~(size_t)255; return p;
    };
    // ybuf (written by GEMM2, bf16) aliases w1t, dead after GEMM1 (stream-ordered).
    u16*   w1t  = (u16*)alloc((size_t)NE * DM * HID * 2);   // 67.1 MB
    u16*   xb   = (u16*)alloc((size_t)T_TOK * DM * 2);      // 16.8 MB
    u16*   w2t  = (u16*)alloc((size_t)NE * DM * HID * 2);   // 67.1 MB
    u16*   hbuf = (u16*)alloc((size_t)RP2 * HID * 2);       // 151 MB
    int*   tok_e = (int*)alloc(2 * T_TOK * 4);
    float* tok_w = (float*)alloc(2 * T_TOK * 4);
    int*   counts  = (int*)alloc(64);
    int*   cursors = (int*)alloc(64);
    int*   pad_off = (int*)alloc(64);
    int*   row_token  = (int*)alloc(RP2 * 4);
    float* row_weight = (float*)alloc(RP2 * 4);
    int*   token_rows = (int*)alloc(2 * T_TOK * 4);
    int*   tile_expert = (int*)alloc(MT128 * 4);
    u16*   ybuf = w1t;                                      // 37.7 MB alias (bf16)

    k_init<<<RP2/256, 256, 0, stream>>>(counts, cursors, row_token);
    k_gate<<<T_TOK/4, 256, 0, stream>>>(x, gw, gb, tok_e, tok_w, counts, xb);
    k_scan<<<1, 256, 0, stream>>>(counts, pad_off, tile_expert);
    k_assign<<<T_TOK/256, 256, 0, stream>>>(tok_e, tok_w, pad_off, cursors, row_token, row_weight, token_rows);
    k_transpose<DM, HID><<<NE*(DM/128)*(HID/64), 256, 0, stream>>>(w1, w1t);
    k_transpose<HID, DM><<<NE*(HID/128)*(DM/64), 256, 0, stream>>>(w2, w2t);
    // GEMM1: 256x256 dbuf, grid 1152 (%8==0), chunked XCD swizzle
    k_gemm256<HID/256, HID, DM, true, true><<<(HID/256)*MT256, 512, 0, stream>>>(
        xb, w1t, b1, (void*)hbuf, row_token, tile_expert, MT256);
    // GEMM2: 128x128, grid 1152 (%8==0), chunked XCD swizzle, bf16 out
    k_gemm128<DM/128, DM, HID, false, false><<<(DM/128)*MT128, 256, 0, stream>>>(
        hbuf, w2t, b2, (void*)ybuf, row_token, tile_expert, MT128);
    k_combine<<<T_TOK/2, 256, 0, stream>>>(ybuf, token_rows, row_weight, out);
}